// Round 1
// baseline (315.909 us; speedup 1.0000x reference)
//
#include <hip/hip_runtime.h>
#include <stdint.h>

// Problem constants (fixed by the reference setup)
#define B_ 32
#define I_ 16384
#define H_ 1024
#define T_ 10
#define M_ 320   // T_*B_  (GEMM M dimension, m = t*32 + b)
#define NW 32    // GEMM per-block n-tile width

typedef __attribute__((ext_vector_type(8))) short short8;  // 8 bf16 (4 VGPRs)
typedef __attribute__((ext_vector_type(4))) float f32x4;
typedef __attribute__((ext_vector_type(4))) unsigned int u32x4;

// ---------------------------------------------------------------------------
// Kernel 1: pack spikes [B][I][T] f32 -> Sbf [M=T*B][I] bf16 (exact: 0/1)
// ---------------------------------------------------------------------------
__global__ __launch_bounds__(256) void pack_s(const float* __restrict__ spikes,
                                              uint16_t* __restrict__ Sbf) {
  __shared__ __align__(16) uint16_t tile[M_ * 40];  // [m][il], il<32 pad->40
  const int i0 = blockIdx.x * 32;
#pragma unroll
  for (int p = 0; p < 10; p++) {
    int e = p * 256 + threadIdx.x;          // f32x4 index
    int b = e / 80;                          // 80 f32x4 per b-row
    int r = e - b * 80;
    f32x4 val = *(const f32x4*)&spikes[(size_t)b * (I_ * T_) + (size_t)i0 * T_ + r * 4];
#pragma unroll
    for (int j = 0; j < 4; j++) {
      int pos = r * 4 + j;                   // pos = il*10 + t
      int il = pos / 10;
      int t = pos - il * 10;
      float f = (j == 0) ? val.x : (j == 1) ? val.y : (j == 2) ? val.z : val.w;
      union { float f; unsigned int u; } cv; cv.f = f;
      tile[(t * 32 + b) * 40 + il] = (uint16_t)(cv.u >> 16);  // exact for 0/1
    }
  }
  __syncthreads();
#pragma unroll
  for (int p = 0; p < 5; p++) {
    int e = p * 256 + threadIdx.x;
    int m = e >> 2, il8 = e & 3;
    u32x4 w = *(const u32x4*)&tile[m * 40 + il8 * 8];
    *(u32x4*)&Sbf[(size_t)m * I_ + i0 + il8 * 8] = w;
  }
}

// ---------------------------------------------------------------------------
// Kernel 2: GEMM  partial[ks][320][1024] = Sbf * (weight*strength)
// 2-term bf16 split (w = hi + lo); fp32-class accuracy.
// Block = 640 thr x full M=320 x NW=32 x kchunk; weight read exactly once.
//
// BK=128 per stage (was 32): W/S loading+packing distributed over 512
// threads (8 waves, was 128/2 waves).  Rationale: the kernel is
// load-concurrency-bound, not BW-bound.  To sustain ~24 GB/s/CU vs ~900cy
// HBM latency needs ~9 KB in flight per CU; the old structure kept ~2 KB
// (measured 1.56 TB/s).  New: 2 blk/CU x 512 thr x 16 dwords ~ 60 KB
// nominal in flight, barrier every 128 K instead of every 32 K.
//
// A-fragments load GLOBAL->REG directly (wave-row mapping IS the MFMA A
// layout); W staged through double-buffered LDS with 1-stage register
// prefetch; ONE barrier per 128-K stage.  W LDS rows = 40 ushorts; write
// phase (u32x4 at word 20*wn+4*ko) and read phase (b128 at word
// 20*l15+4*quad) are conflict-free per 8-lane b128 phase (8 distinct
// 4-word bank starts).  MFMA accumulation order over k identical to the
// BK=32 version (ascending 32-k sub-blocks, hi then lo) -> bit-identical.
// ---------------------------------------------------------------------------
__global__ __launch_bounds__(640, 5) void gemm(const uint16_t* __restrict__ Sbf,
                                               const float* __restrict__ Wg,
                                               const float* __restrict__ Sg,
                                               float* __restrict__ partial,
                                               int kchunk) {
  __shared__ __align__(16) uint16_t WhiL[2][4 * NW * 40];  // 10.24 KB each
  __shared__ __align__(16) uint16_t WloL[2][4 * NW * 40];

  const int nt = blockIdx.x & 31;      // nt fastest: same-ks blocks adjacent
  const int ks = blockIdx.x >> 5;
  const int nbase = nt * NW;
  const int tid = threadIdx.x;
  const int lane = tid & 63, wid = tid >> 6;   // wid 0..9
  const int quad = lane >> 4, l15 = lane & 15;

  const int stages = kchunk >> 7;      // BK = 128 (stages always even here)
  const int kofs = ks * kchunk;

  // A-fragment pointers: lane holds A[m][quad*8 + j] -> 16B contiguous global
  const uint16_t* aptr0 = Sbf + (size_t)(wid * 32 + l15) * I_ + quad * 8;
  const uint16_t* aptr1 = aptr0 + (size_t)16 * I_;

  // W staging mapping (tid < 512): n-column x k-octet (16 octets = 128 k)
  const int wn = tid & 31;
  const int wko = (tid >> 5) & 15;     // k-octet within the 128-k stage

  f32x4 acc[2][2];
#pragma unroll
  for (int a = 0; a < 2; a++)
#pragma unroll
    for (int b = 0; b < 2; b++) acc[a][b] = f32x4{0.f, 0.f, 0.f, 0.f};

  u32x4 afA[2][4], afB[2][4];          // [mtile][ksub] MFMA A fragments
  float wpre[8], spre[8];

  // pack wpre/spre -> hi/lo planes of LDS buffer pn
#define PACK_W(pn)                                                          \
  if (tid < 512) {                                                          \
    unsigned int hw[4], lw[4];                                              \
    _Pragma("unroll")                                                       \
    for (int j2 = 0; j2 < 4; j2++) {                                        \
      unsigned int hh[2], ll[2];                                            \
      _Pragma("unroll")                                                     \
      for (int e = 0; e < 2; e++) {                                         \
        float p = wpre[j2 * 2 + e] * spre[j2 * 2 + e];                      \
        union { float f; unsigned int u; } cv; cv.f = p;                    \
        unsigned int hb = (cv.u + 0x7FFFu + ((cv.u >> 16) & 1u)) >> 16;     \
        union { unsigned int u; float f; } hv; hv.u = hb << 16;             \
        float lo = p - hv.f;                                                \
        union { float f; unsigned int u; } cl; cl.f = lo;                   \
        unsigned int lb = (cl.u + 0x7FFFu + ((cl.u >> 16) & 1u)) >> 16;     \
        hh[e] = hb; ll[e] = lb;                                             \
      }                                                                     \
      hw[j2] = hh[0] | (hh[1] << 16);                                       \
      lw[j2] = ll[0] | (ll[1] << 16);                                       \
    }                                                                       \
    int wofs = (wko >> 2) * (NW * 40) + wn * 40 + (wko & 3) * 8;            \
    *(u32x4*)&WhiL[pn][wofs] = u32x4{hw[0], hw[1], hw[2], hw[3]};           \
    *(u32x4*)&WloL[pn][wofs] = u32x4{lw[0], lw[1], lw[2], lw[3]};           \
  }

#define LOAD_W(kb)                                                          \
  if (tid < 512) {                                                          \
    _Pragma("unroll")                                                       \
    for (int j = 0; j < 8; j++) {                                           \
      size_t g = (size_t)((kb) + wko * 8 + j) * H_ + nbase + wn;            \
      wpre[j] = Wg[g]; spre[j] = Sg[g];                                     \
    }                                                                       \
  }

#define LOAD_A(dst, kb)                                                     \
  {                                                                         \
    _Pragma("unroll")                                                       \
    for (int ku = 0; ku < 4; ku++) {                                        \
      dst[0][ku] = *(const u32x4*)(aptr0 + (kb) + ku * 32);                 \
      dst[1][ku] = *(const u32x4*)(aptr1 + (kb) + ku * 32);                 \
    }                                                                       \
  }

#define COMPUTE(AF, pc)                                                     \
  {                                                                         \
    _Pragma("unroll")                                                       \
    for (int ku = 0; ku < 4; ku++) {                                        \
      short8 a0 = __builtin_bit_cast(short8, AF[0][ku]);                    \
      short8 a1 = __builtin_bit_cast(short8, AF[1][ku]);                    \
      _Pragma("unroll")                                                     \
      for (int tn = 0; tn < 2; tn++) {                                      \
        int n = tn * 16 + l15;                                              \
        short8 bhi = *(const short8*)&WhiL[pc][ku * (NW * 40) + n * 40 + quad * 8]; \
        short8 blo = *(const short8*)&WloL[pc][ku * (NW * 40) + n * 40 + quad * 8]; \
        acc[0][tn] = __builtin_amdgcn_mfma_f32_16x16x32_bf16(a0, bhi, acc[0][tn], 0, 0, 0); \
        acc[0][tn] = __builtin_amdgcn_mfma_f32_16x16x32_bf16(a0, blo, acc[0][tn], 0, 0, 0); \
        acc[1][tn] = __builtin_amdgcn_mfma_f32_16x16x32_bf16(a1, bhi, acc[1][tn], 0, 0, 0); \
        acc[1][tn] = __builtin_amdgcn_mfma_f32_16x16x32_bf16(a1, blo, acc[1][tn], 0, 0, 0); \
      }                                                                     \
    }                                                                       \
  }

  // ---- preamble: load+stage 0, prefetch 1 ----
  LOAD_A(afA, kofs);
  LOAD_W(kofs);
  PACK_W(0);                 // waits wpre(0), writes buf0
  {
    int s1 = (1 < stages) ? 1 : 0;
    int k1 = kofs + (s1 << 7);
    LOAD_A(afB, k1);
    LOAD_W(k1);              // issue only; waited at next PACK_W
  }
  __syncthreads();

  // ---- main loop, unrolled x2 (stages even) ----
  for (int s = 0; s < stages; s += 2) {
    // stage s (even): compute buf0/afA; stage s+1 data -> buf1
    COMPUTE(afA, 0);
    PACK_W(1);
    {
      int s2 = s + 2; if (s2 >= stages) s2 = stages - 1;
      int k2 = kofs + (s2 << 7);
      LOAD_A(afA, k2);
      LOAD_W(k2);
    }
    __syncthreads();
    // stage s+1 (odd): compute buf1/afB; stage s+2 data -> buf0
    COMPUTE(afB, 1);
    PACK_W(0);
    {
      int s3 = s + 3; if (s3 >= stages) s3 = stages - 1;
      int k3 = kofs + (s3 << 7);
      LOAD_A(afB, k3);
      LOAD_W(k3);
    }
    __syncthreads();
  }

  // ---- epilogue: C/D layout col=lane&15, row=quad*4+reg ----
#pragma unroll
  for (int tm = 0; tm < 2; tm++)
#pragma unroll
    for (int tn = 0; tn < 2; tn++) {
      int mrow = wid * 32 + tm * 16 + quad * 4;
      int ncol = nbase + tn * 16 + l15;
      float* dst = partial + ((size_t)ks * M_ + mrow) * H_ + ncol;
      dst[0 * H_] = acc[tm][tn].x;
      dst[1 * H_] = acc[tm][tn].y;
      dst[2 * H_] = acc[tm][tn].z;
      dst[3 * H_] = acc[tm][tn].w;
    }
#undef PACK_W
#undef LOAD_W
#undef LOAD_A
#undef COMPUTE
}

// ---------------------------------------------------------------------------
// Kernel 3: deterministic reduction of K-split partials -> weighted [320][1024]
// Also zeroes the diag region of out (scan runs after us on the stream).
// ---------------------------------------------------------------------------
__global__ __launch_bounds__(256) void reduce_w(const float* __restrict__ partial,
                                                float* __restrict__ weighted,
                                                float* __restrict__ out, int KS) {
  if (blockIdx.x == 0 && threadIdx.x < 30) out[327680 + threadIdx.x] = 0.f;
  int j = (blockIdx.x * 256 + threadIdx.x) * 4;
  f32x4 s = f32x4{0.f, 0.f, 0.f, 0.f};
  for (int k = 0; k < KS; k++) {
    f32x4 p = *(const f32x4*)&partial[(size_t)k * (M_ * H_) + j];
    s += p;
  }
  *(f32x4*)&weighted[j] = s;
}

// ---------------------------------------------------------------------------
// Kernel 4: LIF scan, barrier-free. 64 blocks x 64 thr; lane = (bg,hl):
// thread owns h = blk*16+hl and 8 batches (b = bg*8+j). Cross-bg spike-rate
// reduction via in-wave shfl_xor(16/32); threshold update computed
// identically (deterministically) in the 4 lanes sharing an h.
// ---------------------------------------------------------------------------
__global__ __launch_bounds__(64) void scan(const float* __restrict__ weighted,
                                           const float* __restrict__ threshold,
                                           const float* __restrict__ fre0,
                                           const float* __restrict__ p_tau_mem,
                                           const float* __restrict__ p_tau_syn,
                                           const float* __restrict__ p_target,
                                           const float* __restrict__ p_lr,
                                           float* __restrict__ out) {
  const int lane = threadIdx.x;
  const int hl = lane & 15, bg = lane >> 4;
  const int h = blockIdx.x * 16 + hl;
  const float alpha_mem = expf(-0.001f / p_tau_mem[0]);
  const float alpha_syn = expf(-0.001f / p_tau_syn[0]);
  const float target = p_target[0], lr = p_lr[0];
  float v[8], isyn[8];
#pragma unroll
  for (int j = 0; j < 8; j++) { v[j] = 0.f; isyn[j] = 0.f; }
  float fre = fre0[h];
  float thr = threshold[h];
  for (int t = 0; t < T_; t++) {
    float rsum = 0.f, vsum = 0.f;
#pragma unroll
    for (int j = 0; j < 8; j++) {
      int b = bg * 8 + j;
      float w_in = weighted[(size_t)(t * 32 + b) * H_ + h];
      isyn[j] = alpha_syn * isyn[j] + w_in;
      v[j] = alpha_mem * v[j] + isyn[j];
      float spike = (v[j] >= thr) ? 1.f : 0.f;
      v[j] -= spike * thr;
      out[(size_t)b * (H_ * T_) + (size_t)h * T_ + t] = spike;
      rsum += spike;
      vsum += v[j];
    }
    // sum over the 4 bg-lanes of this h (lanes l, l^16, l^32, l^48)
    float r = rsum;
    r += __shfl_xor(r, 16);
    r += __shfl_xor(r, 32);
    float rate = r * (1.f / 32.f);
    fre = 0.99f * fre + 0.01f * rate;               // identical in 4 lanes
    thr = thr + lr * (fre - target);
    // diagnostics: full-wave sums
    float vv = vsum, rr = rate, tt = thr;
#pragma unroll
    for (int off = 32; off >= 1; off >>= 1) {
      vv += __shfl_xor(vv, off);
      rr += __shfl_xor(rr, off);   // = 4 * sum_h rate
      tt += __shfl_xor(tt, off);   // = 4 * sum_h thr
    }
    if (lane == 0) {
      atomicAdd(&out[327680 + t], vv * (1.f / 32768.f));
      atomicAdd(&out[327690 + t], rr * (1.f / 4096.f));   // /(4*1024)
      atomicAdd(&out[327700 + t], tt * (1.f / 4096.f));
    }
  }
}

// ---------------------------------------------------------------------------
extern "C" void kernel_launch(void* const* d_in, const int* in_sizes, int n_in,
                              void* d_out, int out_size, void* d_ws, size_t ws_size,
                              hipStream_t stream) {
  const float* spikes    = (const float*)d_in[0];
  const float* weight    = (const float*)d_in[1];
  const float* strength  = (const float*)d_in[2];
  const float* threshold = (const float*)d_in[3];
  const float* fre0      = (const float*)d_in[4];
  const float* tau_mem   = (const float*)d_in[5];
  const float* tau_syn   = (const float*)d_in[6];
  const float* target    = (const float*)d_in[7];
  const float* lr        = (const float*)d_in[8];
  float* out = (float*)d_out;

  const size_t sbf_bytes = (size_t)M_ * I_ * 2;   // 10.5 MB bf16 A-matrix
  const size_t slice     = (size_t)M_ * H_ * 4;   // 1.31 MB per K-split partial
  int KS = 16;                                    // shrink if ws is small
  while (KS > 1 && sbf_bytes + (size_t)(KS + 1) * slice > ws_size) KS >>= 1;

  uint16_t* Sbf   = (uint16_t*)d_ws;
  float* partial  = (float*)((char*)d_ws + sbf_bytes);
  float* weighted = (float*)((char*)d_ws + sbf_bytes + (size_t)KS * slice);

  pack_s<<<I_ / 32, 256, 0, stream>>>(spikes, Sbf);
  gemm<<<32 * KS, 640, 0, stream>>>(Sbf, weight, strength, partial, I_ / KS);
  reduce_w<<<(M_ * H_) / 1024, 256, 0, stream>>>(partial, weighted, out, KS);
  scan<<<H_ / 16, 64, 0, stream>>>(weighted, threshold, fre0, tau_mem, tau_syn,
                                   target, lr, out);
}

// Round 2
// 243.535 us; speedup vs baseline: 1.2972x; 1.2972x over previous
//
#include <hip/hip_runtime.h>
#include <stdint.h>

// Problem constants (fixed by the reference setup)
#define B_ 32
#define I_ 16384
#define H_ 1024
#define T_ 10
#define M_ 320   // T_*B_  (GEMM M dimension, m = t*32 + b)
#define NW 32    // GEMM per-block n-tile width

typedef __attribute__((ext_vector_type(8))) short short8;  // 8 bf16 (4 VGPRs)
typedef __attribute__((ext_vector_type(4))) float f32x4;
typedef __attribute__((ext_vector_type(4))) unsigned int u32x4;

// ---------------------------------------------------------------------------
// Kernel 1: pack spikes [B][I][T] f32 -> Sbf [M=T*B][I] bf16 (exact: 0/1)
// ---------------------------------------------------------------------------
__global__ __launch_bounds__(256) void pack_s(const float* __restrict__ spikes,
                                              uint16_t* __restrict__ Sbf) {
  __shared__ __align__(16) uint16_t tile[M_ * 40];  // [m][il], il<32 pad->40
  const int i0 = blockIdx.x * 32;
#pragma unroll
  for (int p = 0; p < 10; p++) {
    int e = p * 256 + threadIdx.x;          // f32x4 index
    int b = e / 80;                          // 80 f32x4 per b-row
    int r = e - b * 80;
    f32x4 val = *(const f32x4*)&spikes[(size_t)b * (I_ * T_) + (size_t)i0 * T_ + r * 4];
#pragma unroll
    for (int j = 0; j < 4; j++) {
      int pos = r * 4 + j;                   // pos = il*10 + t
      int il = pos / 10;
      int t = pos - il * 10;
      float f = (j == 0) ? val.x : (j == 1) ? val.y : (j == 2) ? val.z : val.w;
      union { float f; unsigned int u; } cv; cv.f = f;
      tile[(t * 32 + b) * 40 + il] = (uint16_t)(cv.u >> 16);  // exact for 0/1
    }
  }
  __syncthreads();
#pragma unroll
  for (int p = 0; p < 5; p++) {
    int e = p * 256 + threadIdx.x;
    int m = e >> 2, il8 = e & 3;
    u32x4 w = *(const u32x4*)&tile[m * 40 + il8 * 8];
    *(u32x4*)&Sbf[(size_t)m * I_ + i0 + il8 * 8] = w;
  }
}

// ---------------------------------------------------------------------------
// Kernel 2: GEMM  partial[ks][320][1024] = Sbf * (weight*strength)
// 2-term bf16 split (w = hi + lo); fp32-class accuracy.
// Block = 640 thr x full M=320 x NW=32 x kchunk; weight read exactly once.
//
// ROUND-2 STRUCTURE: the round-0 kernel was limited by __syncthreads()'s
// implicit `s_waitcnt vmcnt(0)` drain (HIP emits it before s_barrier), which
// killed the 1-stage W/S register prefetch every 32 K.  Fix:
//  * raw `s_barrier` with writer-side `s_waitcnt lgkmcnt(0)` ONLY -- global
//    loads into registers stay in flight ACROSS the barrier (T4: counted
//    vmcnt is compiler-inserted for the register deps; never a full drain).
//  * BK=128 per stage, W/S load+pack spread over 512 threads (8 waves).
//  * A-fragments: just-in-time per-32k global->reg loads (Sbf is L2/L3
//    resident) with a 1-subtile ping-pong.  NO stage-level A register
//    buffer -- round 1 proved that spills (WRITE_SIZE 20->113 MB).
// LDS W rows = 40 ushorts: write phase (u32x4 @ word 20*wn+4*ko) and read
// phase (b128 @ word 20*l15+4*quad) are conflict-free per 8-lane phase.
// MFMA accumulation order over k identical to round 0 (ascending 32-k
// subtiles, hi then lo) -> bit-identical output.
// ---------------------------------------------------------------------------
__global__ __launch_bounds__(640, 5) void gemm(const uint16_t* __restrict__ Sbf,
                                               const float* __restrict__ Wg,
                                               const float* __restrict__ Sg,
                                               float* __restrict__ partial,
                                               int kchunk) {
  __shared__ __align__(16) uint16_t WhiL[2][4 * NW * 40];  // 10.24 KB each
  __shared__ __align__(16) uint16_t WloL[2][4 * NW * 40];

  const int nt = blockIdx.x & 31;      // nt fastest: same-ks blocks adjacent
  const int ks = blockIdx.x >> 5;
  const int nbase = nt * NW;
  const int tid = threadIdx.x;
  const int lane = tid & 63, wid = tid >> 6;   // wid 0..9
  const int quad = lane >> 4, l15 = lane & 15;

  const int stages = kchunk >> 7;      // BK = 128
  const int kofs = ks * kchunk;

  // A-fragment pointers: lane holds A[m][quad*8 + j] -> 16B contiguous global
  const uint16_t* aptr0 = Sbf + (size_t)(wid * 32 + l15) * I_ + quad * 8;
  const uint16_t* aptr1 = aptr0 + (size_t)16 * I_;

  // W staging mapping (tid < 512): n-column x k-octet (16 octets = 128 k)
  const int wn = tid & 31;
  const int wko = (tid >> 5) & 15;     // k-octet within the 128-k stage

  f32x4 acc[2][2];
#pragma unroll
  for (int a = 0; a < 2; a++)
#pragma unroll
    for (int b = 0; b < 2; b++) acc[a][b] = f32x4{0.f, 0.f, 0.f, 0.f};

  u32x4 afC[2], afN[2];                // A ping-pong: current / next 32-k subtile
  float wpre[8], spre[8];

  // Raw barrier: LDS-write visibility only; vmem loads stay in flight.
#define BAR()                                                               \
  do {                                                                      \
    asm volatile("s_waitcnt lgkmcnt(0)" ::: "memory");                      \
    __builtin_amdgcn_s_barrier();                                           \
    __builtin_amdgcn_sched_barrier(0);                                      \
  } while (0)

  // pack wpre/spre -> hi/lo planes of LDS buffer pn
#define PACK_W(pn)                                                          \
  if (tid < 512) {                                                          \
    unsigned int hw[4], lw[4];                                              \
    _Pragma("unroll")                                                       \
    for (int j2 = 0; j2 < 4; j2++) {                                        \
      unsigned int hh[2], ll[2];                                            \
      _Pragma("unroll")                                                     \
      for (int e = 0; e < 2; e++) {                                         \
        float p = wpre[j2 * 2 + e] * spre[j2 * 2 + e];                      \
        union { float f; unsigned int u; } cv; cv.f = p;                    \
        unsigned int hb = (cv.u + 0x7FFFu + ((cv.u >> 16) & 1u)) >> 16;     \
        union { unsigned int u; float f; } hv; hv.u = hb << 16;             \
        float lo = p - hv.f;                                                \
        union { float f; unsigned int u; } cl; cl.f = lo;                   \
        unsigned int lb = (cl.u + 0x7FFFu + ((cl.u >> 16) & 1u)) >> 16;     \
        hh[e] = hb; ll[e] = lb;                                             \
      }                                                                     \
      hw[j2] = hh[0] | (hh[1] << 16);                                       \
      lw[j2] = ll[0] | (ll[1] << 16);                                       \
    }                                                                       \
    int wofs = (wko >> 2) * (NW * 40) + wn * 40 + (wko & 3) * 8;            \
    *(u32x4*)&WhiL[pn][wofs] = u32x4{hw[0], hw[1], hw[2], hw[3]};           \
    *(u32x4*)&WloL[pn][wofs] = u32x4{lw[0], lw[1], lw[2], lw[3]};           \
  }

#define LOAD_W(kb)                                                          \
  if (tid < 512) {                                                          \
    _Pragma("unroll")                                                       \
    for (int j = 0; j < 8; j++) {                                           \
      size_t g = (size_t)((kb) + wko * 8 + j) * H_ + nbase + wn;            \
      wpre[j] = Wg[g]; spre[j] = Sg[g];                                     \
    }                                                                       \
  }

  // ---- preamble ----
  afC[0] = *(const u32x4*)(aptr0 + kofs);          // A subtile 0
  afC[1] = *(const u32x4*)(aptr1 + kofs);
  LOAD_W(kofs);              // stage 0 W/S
  PACK_W(0);                 // waits stage-0 loads, fills buf0
  if (stages > 1) LOAD_W(kofs + (1 << 7));         // stage 1 W/S: issue only
  BAR();

  // ---- main loop ----
  const int lastA = stages * 4 - 1;                // last 32-k subtile index
  for (int s = 0; s < stages; ++s) {
    const int pc = s & 1;
#pragma unroll
    for (int ku = 0; ku < 4; ++ku) {
      // prefetch next A subtile (clamped duplicate at the tail; harmless)
      int nidx = s * 4 + ku + 1;
      if (nidx > lastA) nidx = lastA;
      const int nkb = kofs + nidx * 32;
      afN[0] = *(const u32x4*)(aptr0 + nkb);
      afN[1] = *(const u32x4*)(aptr1 + nkb);
      short8 a0 = __builtin_bit_cast(short8, afC[0]);
      short8 a1 = __builtin_bit_cast(short8, afC[1]);
#pragma unroll
      for (int tn = 0; tn < 2; ++tn) {
        int n = tn * 16 + l15;
        short8 bhi = *(const short8*)&WhiL[pc][ku * (NW * 40) + n * 40 + quad * 8];
        short8 blo = *(const short8*)&WloL[pc][ku * (NW * 40) + n * 40 + quad * 8];
        acc[0][tn] = __builtin_amdgcn_mfma_f32_16x16x32_bf16(a0, bhi, acc[0][tn], 0, 0, 0);
        acc[0][tn] = __builtin_amdgcn_mfma_f32_16x16x32_bf16(a0, blo, acc[0][tn], 0, 0, 0);
        acc[1][tn] = __builtin_amdgcn_mfma_f32_16x16x32_bf16(a1, bhi, acc[1][tn], 0, 0, 0);
        acc[1][tn] = __builtin_amdgcn_mfma_f32_16x16x32_bf16(a1, blo, acc[1][tn], 0, 0, 0);
      }
      afC[0] = afN[0]; afC[1] = afN[1];
    }
    if (s + 1 < stages) {
      PACK_W(pc ^ 1);        // waits stage s+1 W loads (issued stage s-1/pre)
      if (s + 2 < stages) LOAD_W(kofs + ((s + 2) << 7));
      BAR();
    }
  }

  // ---- epilogue: C/D layout col=lane&15, row=quad*4+reg ----
#pragma unroll
  for (int tm = 0; tm < 2; tm++)
#pragma unroll
    for (int tn = 0; tn < 2; tn++) {
      int mrow = wid * 32 + tm * 16 + quad * 4;
      int ncol = nbase + tn * 16 + l15;
      float* dst = partial + ((size_t)ks * M_ + mrow) * H_ + ncol;
      dst[0 * H_] = acc[tm][tn].x;
      dst[1 * H_] = acc[tm][tn].y;
      dst[2 * H_] = acc[tm][tn].z;
      dst[3 * H_] = acc[tm][tn].w;
    }
#undef PACK_W
#undef LOAD_W
#undef BAR
}

// ---------------------------------------------------------------------------
// Kernel 3: deterministic reduction of K-split partials -> weighted [320][1024]
// Also zeroes the diag region of out (scan runs after us on the stream).
// ---------------------------------------------------------------------------
__global__ __launch_bounds__(256) void reduce_w(const float* __restrict__ partial,
                                                float* __restrict__ weighted,
                                                float* __restrict__ out, int KS) {
  if (blockIdx.x == 0 && threadIdx.x < 30) out[327680 + threadIdx.x] = 0.f;
  int j = (blockIdx.x * 256 + threadIdx.x) * 4;
  f32x4 s = f32x4{0.f, 0.f, 0.f, 0.f};
  for (int k = 0; k < KS; k++) {
    f32x4 p = *(const f32x4*)&partial[(size_t)k * (M_ * H_) + j];
    s += p;
  }
  *(f32x4*)&weighted[j] = s;
}

// ---------------------------------------------------------------------------
// Kernel 4: LIF scan, barrier-free. 64 blocks x 64 thr; lane = (bg,hl):
// thread owns h = blk*16+hl and 8 batches (b = bg*8+j). Cross-bg spike-rate
// reduction via in-wave shfl_xor(16/32); threshold update computed
// identically (deterministically) in the 4 lanes sharing an h.
// ---------------------------------------------------------------------------
__global__ __launch_bounds__(64) void scan(const float* __restrict__ weighted,
                                           const float* __restrict__ threshold,
                                           const float* __restrict__ fre0,
                                           const float* __restrict__ p_tau_mem,
                                           const float* __restrict__ p_tau_syn,
                                           const float* __restrict__ p_target,
                                           const float* __restrict__ p_lr,
                                           float* __restrict__ out) {
  const int lane = threadIdx.x;
  const int hl = lane & 15, bg = lane >> 4;
  const int h = blockIdx.x * 16 + hl;
  const float alpha_mem = expf(-0.001f / p_tau_mem[0]);
  const float alpha_syn = expf(-0.001f / p_tau_syn[0]);
  const float target = p_target[0], lr = p_lr[0];
  float v[8], isyn[8];
#pragma unroll
  for (int j = 0; j < 8; j++) { v[j] = 0.f; isyn[j] = 0.f; }
  float fre = fre0[h];
  float thr = threshold[h];
  for (int t = 0; t < T_; t++) {
    float rsum = 0.f, vsum = 0.f;
#pragma unroll
    for (int j = 0; j < 8; j++) {
      int b = bg * 8 + j;
      float w_in = weighted[(size_t)(t * 32 + b) * H_ + h];
      isyn[j] = alpha_syn * isyn[j] + w_in;
      v[j] = alpha_mem * v[j] + isyn[j];
      float spike = (v[j] >= thr) ? 1.f : 0.f;
      v[j] -= spike * thr;
      out[(size_t)b * (H_ * T_) + (size_t)h * T_ + t] = spike;
      rsum += spike;
      vsum += v[j];
    }
    // sum over the 4 bg-lanes of this h (lanes l, l^16, l^32, l^48)
    float r = rsum;
    r += __shfl_xor(r, 16);
    r += __shfl_xor(r, 32);
    float rate = r * (1.f / 32.f);
    fre = 0.99f * fre + 0.01f * rate;               // identical in 4 lanes
    thr = thr + lr * (fre - target);
    // diagnostics: full-wave sums
    float vv = vsum, rr = rate, tt = thr;
#pragma unroll
    for (int off = 32; off >= 1; off >>= 1) {
      vv += __shfl_xor(vv, off);
      rr += __shfl_xor(rr, off);   // = 4 * sum_h rate
      tt += __shfl_xor(tt, off);   // = 4 * sum_h thr
    }
    if (lane == 0) {
      atomicAdd(&out[327680 + t], vv * (1.f / 32768.f));
      atomicAdd(&out[327690 + t], rr * (1.f / 4096.f));   // /(4*1024)
      atomicAdd(&out[327700 + t], tt * (1.f / 4096.f));
    }
  }
}

// ---------------------------------------------------------------------------
extern "C" void kernel_launch(void* const* d_in, const int* in_sizes, int n_in,
                              void* d_out, int out_size, void* d_ws, size_t ws_size,
                              hipStream_t stream) {
  const float* spikes    = (const float*)d_in[0];
  const float* weight    = (const float*)d_in[1];
  const float* strength  = (const float*)d_in[2];
  const float* threshold = (const float*)d_in[3];
  const float* fre0      = (const float*)d_in[4];
  const float* tau_mem   = (const float*)d_in[5];
  const float* tau_syn   = (const float*)d_in[6];
  const float* target    = (const float*)d_in[7];
  const float* lr        = (const float*)d_in[8];
  float* out = (float*)d_out;

  const size_t sbf_bytes = (size_t)M_ * I_ * 2;   // 10.5 MB bf16 A-matrix
  const size_t slice     = (size_t)M_ * H_ * 4;   // 1.31 MB per K-split partial
  int KS = 16;                                    // shrink if ws is small
  while (KS > 1 && sbf_bytes + (size_t)(KS + 1) * slice > ws_size) KS >>= 1;

  uint16_t* Sbf   = (uint16_t*)d_ws;
  float* partial  = (float*)((char*)d_ws + sbf_bytes);
  float* weighted = (float*)((char*)d_ws + sbf_bytes + (size_t)KS * slice);

  pack_s<<<I_ / 32, 256, 0, stream>>>(spikes, Sbf);
  gemm<<<32 * KS, 640, 0, stream>>>(Sbf, weight, strength, partial, I_ / KS);
  reduce_w<<<(M_ * H_) / 1024, 256, 0, stream>>>(partial, weighted, out, KS);
  scan<<<H_ / 16, 64, 0, stream>>>(weighted, threshold, fre0, tau_mem, tau_syn,
                                   target, lr, out);
}

// Round 3
// 227.352 us; speedup vs baseline: 1.3895x; 1.0712x over previous
//
#include <hip/hip_runtime.h>
#include <stdint.h>

// Problem constants (fixed by the reference setup)
#define B_ 32
#define I_ 16384
#define H_ 1024
#define T_ 10
#define M_ 320   // T_*B_  (GEMM M dimension, m = t*32 + b)
#define NW 32    // GEMM per-block n-tile width
#define BK 64    // K rows per pipeline stage
#define RB 3     // raw-stage ring depth

typedef __attribute__((ext_vector_type(8))) short short8;  // 8 bf16 (4 VGPRs)
typedef __attribute__((ext_vector_type(4))) float f32x4;
typedef __attribute__((ext_vector_type(4))) unsigned int u32x4;

// ---------------------------------------------------------------------------
// Kernel 1: pack spikes [B][I][T] f32 -> Sbf [M=T*B][I] bf16 (exact: 0/1)
// ---------------------------------------------------------------------------
__global__ __launch_bounds__(256) void pack_s(const float* __restrict__ spikes,
                                              uint16_t* __restrict__ Sbf) {
  __shared__ __align__(16) uint16_t tile[M_ * 40];  // [m][il], il<32 pad->40
  const int i0 = blockIdx.x * 32;
#pragma unroll
  for (int p = 0; p < 10; p++) {
    int e = p * 256 + threadIdx.x;          // f32x4 index
    int b = e / 80;                          // 80 f32x4 per b-row
    int r = e - b * 80;
    f32x4 val = *(const f32x4*)&spikes[(size_t)b * (I_ * T_) + (size_t)i0 * T_ + r * 4];
#pragma unroll
    for (int j = 0; j < 4; j++) {
      int pos = r * 4 + j;                   // pos = il*10 + t
      int il = pos / 10;
      int t = pos - il * 10;
      float f = (j == 0) ? val.x : (j == 1) ? val.y : (j == 2) ? val.z : val.w;
      union { float f; unsigned int u; } cv; cv.f = f;
      tile[(t * 32 + b) * 40 + il] = (uint16_t)(cv.u >> 16);  // exact for 0/1
    }
  }
  __syncthreads();
#pragma unroll
  for (int p = 0; p < 5; p++) {
    int e = p * 256 + threadIdx.x;
    int m = e >> 2, il8 = e & 3;
    u32x4 w = *(const u32x4*)&tile[m * 40 + il8 * 8];
    *(u32x4*)&Sbf[(size_t)m * I_ + i0 + il8 * 8] = w;
  }
}

// ---------------------------------------------------------------------------
// Kernel 2: GEMM  partial[ks][320][1024] = Sbf * (weight*strength)
// 2-term bf16 split (w = hi + lo); fp32-class accuracy.
//
// ROUND-3 STRUCTURE (T3/T4): rounds 0-2 all pinned HBM at ~1.5 TB/s because
// load-issue(s+2) was serialized behind load-ARRIVAL(s+1) (PACK's wait gates
// the next LOAD_W) -> never more than ~1 stage in flight.  Fix:
//  * raw fp32 W/S tiles stream into LDS via global_load_lds (no dest regs,
//    no register-liveness gating), ring of RB=3 buffers, issue for stage
//    s+3 at stage s -> 2-stage lead, decoupled from arrival.
//  * counted s_waitcnt vmcnt(N) (never 0 mid-loop) BEFORE each barrier:
//    each wave guarantees its own staged loads landed, barrier extends the
//    guarantee to all waves (cross-wave raw reads in PACK are safe).
//    Steady-state ledger per loader wave: A(s+1)=4 instr + W(s+3)=2 instr
//    outstanding -> vmcnt(6); tail stages (no W issue) -> vmcnt(4).
//  * PACK phase: 256 threads read raw LDS (2-way conflict = free), hi/lo
//    split, write the proven conflict-free 40-ushort-row fragment layout.
//  * A-fragments: per-stage 4x dwordx4 global->reg (L2/L3-resident Sbf),
//    issued AFTER compute consumed the previous stage (no extra liveness).
// MFMA k-order identical to rounds 0-2 (ascending 32-k subtiles, hi then
// lo) -> bit-identical output.
// LDS: raw 2*RB*8KB = 48KB + packed 2*2*5.12KB = 20.5KB -> 68.6KB,
// 2 blocks/CU.
// ---------------------------------------------------------------------------
__global__ __launch_bounds__(640, 5) void gemm(const uint16_t* __restrict__ Sbf,
                                               const float* __restrict__ Wg,
                                               const float* __restrict__ Sg,
                                               float* __restrict__ partial,
                                               int kchunk) {
  __shared__ __align__(16) float rawW[RB][BK * NW];        // [64][32] f32, 8KB
  __shared__ __align__(16) float rawS[RB][BK * NW];
  __shared__ __align__(16) uint16_t WhiL[2][2 * NW * 40];  // 5.12KB per buf
  __shared__ __align__(16) uint16_t WloL[2][2 * NW * 40];

  const int nt = blockIdx.x & 31;      // nt fastest: same-ks blocks adjacent
  const int ks = blockIdx.x >> 5;
  const int nbase = nt * NW;
  const int tid = threadIdx.x;
  const int lane = tid & 63, wid = tid >> 6;   // wid 0..9
  const int quad = lane >> 4, l15 = lane & 15;

  const int stages = kchunk >> 6;      // BK = 64 (>= 16 always)
  const int kofs = ks * kchunk;

  // A-fragment pointers: lane holds A[m][quad*8 + j] -> 16B contiguous global
  const uint16_t* aptr0 = Sbf + (size_t)(wid * 32 + l15) * I_ + quad * 8;
  const uint16_t* aptr1 = aptr0 + (size_t)16 * I_;

  // Raw staging: wave w (0..7) stages rows w*8..w*8+7 of the 64x32 tile.
  // Per lane: global element (w*8 + (lane>>3))*H + nbase + (lane&7)*4;
  // LDS dest is wave-uniform base (w*1024 B), HW adds lane*16.
  const size_t gstage = (size_t)(wid * 8 + (lane >> 3)) * H_ + nbase + (lane & 7) * 4;

  // Packers: 256 threads; wn = column, wko = 8-row octet (0..7)
  const int wn = tid & 31;
  const int wko = tid >> 5;            // used only when tid < 256

  f32x4 acc[2][2];
#pragma unroll
  for (int a = 0; a < 2; a++)
#pragma unroll
    for (int b = 0; b < 2; b++) acc[a][b] = f32x4{0.f, 0.f, 0.f, 0.f};

  u32x4 af[2][2];                      // [mtile][ksub] current-stage A frags

#define ISSUE_W(sidx)                                                       \
  if (tid < 512) {                                                          \
    const int _rb = (sidx) % RB;                                            \
    const float* gw = Wg + (size_t)(kofs + (sidx) * BK) * H_ + gstage;      \
    const float* gs = Sg + (size_t)(kofs + (sidx) * BK) * H_ + gstage;      \
    __builtin_amdgcn_global_load_lds(                                       \
        (const __attribute__((address_space(1))) void*)gw,                  \
        (__attribute__((address_space(3))) void*)&rawW[_rb][wid * 256],     \
        16, 0, 0);                                                          \
    __builtin_amdgcn_global_load_lds(                                       \
        (const __attribute__((address_space(1))) void*)gs,                  \
        (__attribute__((address_space(3))) void*)&rawS[_rb][wid * 256],     \
        16, 0, 0);                                                          \
  }

#define ISSUE_A(sidx)                                                       \
  {                                                                         \
    const int _kb = kofs + (sidx) * BK;                                     \
    af[0][0] = *(const u32x4*)(aptr0 + _kb);                                \
    af[1][0] = *(const u32x4*)(aptr1 + _kb);                                \
    af[0][1] = *(const u32x4*)(aptr0 + _kb + 32);                           \
    af[1][1] = *(const u32x4*)(aptr1 + _kb + 32);                           \
  }

  // Pack raw[(sidx)%RB] -> hi/lo planes of packed buffer (sidx)&1.
  // Thread handles 8 consecutive k (rows wko*8..+7) at column wn; identical
  // value->position mapping to rounds 0-2 (bit-identical results).
#define PACK_W(sidx)                                                        \
  if (tid < 256) {                                                          \
    const int _rb = (sidx) % RB;                                            \
    const int _pn = (sidx) & 1;                                             \
    unsigned int hw[4], lw[4];                                              \
    _Pragma("unroll")                                                       \
    for (int j2 = 0; j2 < 4; j2++) {                                        \
      unsigned int hh[2], ll[2];                                            \
      _Pragma("unroll")                                                     \
      for (int e = 0; e < 2; e++) {                                         \
        int r = wko * 8 + j2 * 2 + e;                                       \
        float p = rawW[_rb][r * 32 + wn] * rawS[_rb][r * 32 + wn];          \
        union { float f; unsigned int u; } cv; cv.f = p;                    \
        unsigned int hb = (cv.u + 0x7FFFu + ((cv.u >> 16) & 1u)) >> 16;     \
        union { unsigned int u; float f; } hv; hv.u = hb << 16;             \
        float lo = p - hv.f;                                                \
        union { float f; unsigned int u; } cl; cl.f = lo;                   \
        unsigned int lb = (cl.u + 0x7FFFu + ((cl.u >> 16) & 1u)) >> 16;     \
        hh[e] = hb; ll[e] = lb;                                             \
      }                                                                     \
      hw[j2] = hh[0] | (hh[1] << 16);                                       \
      lw[j2] = ll[0] | (ll[1] << 16);                                       \
    }                                                                       \
    int wofs = (wko >> 2) * (NW * 40) + wn * 40 + (wko & 3) * 8;            \
    *(u32x4*)&WhiL[_pn][wofs] = u32x4{hw[0], hw[1], hw[2], hw[3]};          \
    *(u32x4*)&WloL[_pn][wofs] = u32x4{lw[0], lw[1], lw[2], lw[3]};          \
  }

#define COMPUTE(pc)                                                         \
  {                                                                         \
    _Pragma("unroll")                                                       \
    for (int ku = 0; ku < 2; ++ku) {                                        \
      short8 a0 = __builtin_bit_cast(short8, af[0][ku]);                    \
      short8 a1 = __builtin_bit_cast(short8, af[1][ku]);                    \
      _Pragma("unroll")                                                     \
      for (int tn = 0; tn < 2; ++tn) {                                      \
        int n = tn * 16 + l15;                                              \
        short8 bhi = *(const short8*)&WhiL[pc][ku * (NW * 40) + n * 40 + quad * 8]; \
        short8 blo = *(const short8*)&WloL[pc][ku * (NW * 40) + n * 40 + quad * 8]; \
        acc[0][tn] = __builtin_amdgcn_mfma_f32_16x16x32_bf16(a0, bhi, acc[0][tn], 0, 0, 0); \
        acc[0][tn] = __builtin_amdgcn_mfma_f32_16x16x32_bf16(a0, blo, acc[0][tn], 0, 0, 0); \
        acc[1][tn] = __builtin_amdgcn_mfma_f32_16x16x32_bf16(a1, bhi, acc[1][tn], 0, 0, 0); \
        acc[1][tn] = __builtin_amdgcn_mfma_f32_16x16x32_bf16(a1, blo, acc[1][tn], 0, 0, 0); \
      }                                                                     \
    }                                                                       \
  }

  // ---- prologue: W0,W1,A0,W2 in flight; pack stage 0 ----
  ISSUE_W(0);
  ISSUE_W(1);
  ISSUE_A(0);
  ISSUE_W(2);
  if (tid < 512) asm volatile("s_waitcnt vmcnt(8)" ::: "memory");  // W0 landed
  __builtin_amdgcn_s_barrier();
  __builtin_amdgcn_sched_barrier(0);
  PACK_W(0);
  if (tid < 512) asm volatile("s_waitcnt vmcnt(6)" ::: "memory");  // W1 landed
  asm volatile("s_waitcnt lgkmcnt(0)" ::: "memory");
  __builtin_amdgcn_s_barrier();
  __builtin_amdgcn_sched_barrier(0);

  // ---- main loop: one barrier per stage; vmcnt never drained to 0 ----
  for (int s = 0; s < stages; ++s) {
    const int pc = s & 1;
    if (s + 1 < stages) PACK_W(s + 1);       // raw (s+1)%RB -> packed pc^1
    __builtin_amdgcn_sched_barrier(0);
    COMPUTE(pc);
    __builtin_amdgcn_sched_barrier(0);
    if (s + 1 < stages) ISSUE_A(s + 1);
    if (s + 3 < stages) {
      ISSUE_W(s + 3);                        // into raw (s+3)%RB (== s%RB, freed)
      if (tid < 512) asm volatile("s_waitcnt vmcnt(6)" ::: "memory");  // W(s+2) landed
    } else if (s + 1 < stages) {
      if (tid < 512) asm volatile("s_waitcnt vmcnt(4)" ::: "memory");  // all W landed
    }
    if (s + 1 < stages) {
      asm volatile("s_waitcnt lgkmcnt(0)" ::: "memory");
      __builtin_amdgcn_s_barrier();
      __builtin_amdgcn_sched_barrier(0);
    }
  }

  // ---- epilogue: C/D layout col=lane&15, row=quad*4+reg ----
#pragma unroll
  for (int tm = 0; tm < 2; tm++)
#pragma unroll
    for (int tn = 0; tn < 2; tn++) {
      int mrow = wid * 32 + tm * 16 + quad * 4;
      int ncol = nbase + tn * 16 + l15;
      float* dst = partial + ((size_t)ks * M_ + mrow) * H_ + ncol;
      dst[0 * H_] = acc[tm][tn].x;
      dst[1 * H_] = acc[tm][tn].y;
      dst[2 * H_] = acc[tm][tn].z;
      dst[3 * H_] = acc[tm][tn].w;
    }
#undef PACK_W
#undef ISSUE_W
#undef ISSUE_A
#undef COMPUTE
}

// ---------------------------------------------------------------------------
// Kernel 3: deterministic reduction of K-split partials -> weighted [320][1024]
// Also zeroes the diag region of out (scan runs after us on the stream).
// ---------------------------------------------------------------------------
__global__ __launch_bounds__(256) void reduce_w(const float* __restrict__ partial,
                                                float* __restrict__ weighted,
                                                float* __restrict__ out, int KS) {
  if (blockIdx.x == 0 && threadIdx.x < 30) out[327680 + threadIdx.x] = 0.f;
  int j = (blockIdx.x * 256 + threadIdx.x) * 4;
  f32x4 s = f32x4{0.f, 0.f, 0.f, 0.f};
  for (int k = 0; k < KS; k++) {
    f32x4 p = *(const f32x4*)&partial[(size_t)k * (M_ * H_) + j];
    s += p;
  }
  *(f32x4*)&weighted[j] = s;
}

// ---------------------------------------------------------------------------
// Kernel 4: LIF scan, barrier-free. 64 blocks x 64 thr; lane = (bg,hl):
// thread owns h = blk*16+hl and 8 batches (b = bg*8+j). Cross-bg spike-rate
// reduction via in-wave shfl_xor(16/32); threshold update computed
// identically (deterministically) in the 4 lanes sharing an h.
// ---------------------------------------------------------------------------
__global__ __launch_bounds__(64) void scan(const float* __restrict__ weighted,
                                           const float* __restrict__ threshold,
                                           const float* __restrict__ fre0,
                                           const float* __restrict__ p_tau_mem,
                                           const float* __restrict__ p_tau_syn,
                                           const float* __restrict__ p_target,
                                           const float* __restrict__ p_lr,
                                           float* __restrict__ out) {
  const int lane = threadIdx.x;
  const int hl = lane & 15, bg = lane >> 4;
  const int h = blockIdx.x * 16 + hl;
  const float alpha_mem = expf(-0.001f / p_tau_mem[0]);
  const float alpha_syn = expf(-0.001f / p_tau_syn[0]);
  const float target = p_target[0], lr = p_lr[0];
  float v[8], isyn[8];
#pragma unroll
  for (int j = 0; j < 8; j++) { v[j] = 0.f; isyn[j] = 0.f; }
  float fre = fre0[h];
  float thr = threshold[h];
  for (int t = 0; t < T_; t++) {
    float rsum = 0.f, vsum = 0.f;
#pragma unroll
    for (int j = 0; j < 8; j++) {
      int b = bg * 8 + j;
      float w_in = weighted[(size_t)(t * 32 + b) * H_ + h];
      isyn[j] = alpha_syn * isyn[j] + w_in;
      v[j] = alpha_mem * v[j] + isyn[j];
      float spike = (v[j] >= thr) ? 1.f : 0.f;
      v[j] -= spike * thr;
      out[(size_t)b * (H_ * T_) + (size_t)h * T_ + t] = spike;
      rsum += spike;
      vsum += v[j];
    }
    // sum over the 4 bg-lanes of this h (lanes l, l^16, l^32, l^48)
    float r = rsum;
    r += __shfl_xor(r, 16);
    r += __shfl_xor(r, 32);
    float rate = r * (1.f / 32.f);
    fre = 0.99f * fre + 0.01f * rate;               // identical in 4 lanes
    thr = thr + lr * (fre - target);
    // diagnostics: full-wave sums
    float vv = vsum, rr = rate, tt = thr;
#pragma unroll
    for (int off = 32; off >= 1; off >>= 1) {
      vv += __shfl_xor(vv, off);
      rr += __shfl_xor(rr, off);   // = 4 * sum_h rate
      tt += __shfl_xor(tt, off);   // = 4 * sum_h thr
    }
    if (lane == 0) {
      atomicAdd(&out[327680 + t], vv * (1.f / 32768.f));
      atomicAdd(&out[327690 + t], rr * (1.f / 4096.f));   // /(4*1024)
      atomicAdd(&out[327700 + t], tt * (1.f / 4096.f));
    }
  }
}

// ---------------------------------------------------------------------------
extern "C" void kernel_launch(void* const* d_in, const int* in_sizes, int n_in,
                              void* d_out, int out_size, void* d_ws, size_t ws_size,
                              hipStream_t stream) {
  const float* spikes    = (const float*)d_in[0];
  const float* weight    = (const float*)d_in[1];
  const float* strength  = (const float*)d_in[2];
  const float* threshold = (const float*)d_in[3];
  const float* fre0      = (const float*)d_in[4];
  const float* tau_mem   = (const float*)d_in[5];
  const float* tau_syn   = (const float*)d_in[6];
  const float* target    = (const float*)d_in[7];
  const float* lr        = (const float*)d_in[8];
  float* out = (float*)d_out;

  const size_t sbf_bytes = (size_t)M_ * I_ * 2;   // 10.5 MB bf16 A-matrix
  const size_t slice     = (size_t)M_ * H_ * 4;   // 1.31 MB per K-split partial
  int KS = 16;                                    // shrink if ws is small
  while (KS > 1 && sbf_bytes + (size_t)(KS + 1) * slice > ws_size) KS >>= 1;

  uint16_t* Sbf   = (uint16_t*)d_ws;
  float* partial  = (float*)((char*)d_ws + sbf_bytes);
  float* weighted = (float*)((char*)d_ws + sbf_bytes + (size_t)KS * slice);

  pack_s<<<I_ / 32, 256, 0, stream>>>(spikes, Sbf);
  gemm<<<32 * KS, 640, 0, stream>>>(Sbf, weight, strength, partial, I_ / KS);
  reduce_w<<<(M_ * H_) / 1024, 256, 0, stream>>>(partial, weighted, out, KS);
  scan<<<H_ / 16, 64, 0, stream>>>(weighted, threshold, fre0, tau_mem, tau_syn,
                                   target, lr, out);
}